// Round 1
// baseline (36953.625 us; speedup 1.0000x reference)
//
#include <hip/hip_runtime.h>

typedef unsigned short u16;
typedef unsigned int u32;
typedef short v8s __attribute__((ext_vector_type(8)));
typedef float v4f __attribute__((ext_vector_type(4)));

#define DEV static __device__ __forceinline__

DEV float bf2f(u16 u) { union { u32 i; float f; } v; v.i = ((u32)u) << 16; return v.f; }
DEV u16 f2bf(float f) {
  union { float f; u32 i; } v; v.f = f;
  u32 i = v.i + 0x7FFFu + ((v.i >> 16) & 1u);
  return (u16)(i >> 16);
}
DEV float sigm(float x) { return 1.0f / (1.0f + __expf(-x)); }
DEV v4f mfma16(v8s a, v8s b, v4f c) {
  return __builtin_amdgcn_mfma_f32_16x16x32_bf16(a, b, c, 0, 0, 0);
}
DEV v8s ld8(const u16* p) { return *(const v8s*)p; }

// ---------------- grid barrier (flag array, agent scope) ----------------
DEV void gbar(u32* flags, int nwg, int wg, u32 tgt) {
  __syncthreads();
  if (threadIdx.x < 64) {
    if (threadIdx.x == 0) {
      __threadfence();
      __hip_atomic_store(flags + wg, tgt, __ATOMIC_RELEASE, __HIP_MEMORY_SCOPE_AGENT);
    }
    const int lane = threadIdx.x;
    for (;;) {
      bool ok = true;
      for (int i = lane; i < nwg; i += 64) {
        u32 v = __hip_atomic_load(flags + i, __ATOMIC_RELAXED, __HIP_MEMORY_SCOPE_AGENT);
        ok &= (v >= tgt);
      }
      if (__ballot((int)ok) == ~0ull) break;
      __builtin_amdgcn_s_sleep(1);
    }
    __threadfence();
  }
  __syncthreads();
}

// ---------------- small utility kernels ----------------
__global__ void k_zero(uint4* p, int n) {
  int i = blockIdx.x * 256 + threadIdx.x;
  if (i < n) p[i] = make_uint4(0, 0, 0, 0);
}

__global__ void k_cvt(const float* __restrict__ s, u16* __restrict__ d, int n) {
  int i = (blockIdx.x * 256 + threadIdx.x) * 4;
  if (i < n) {
    float4 v = *(const float4*)(s + i);
    ushort4 u;
    u.x = f2bf(v.x); u.y = f2bf(v.y); u.z = f2bf(v.z); u.w = f2bf(v.w);
    *(ushort4*)(d + i) = u;
  }
}

// fused [Wih|Whh] with gate-interleaved row perm: r -> (block=r>>6)*16 + (r&15), gate=(r>>4)&3
__global__ void k_pack_enc(const float* __restrict__ Wih, const float* __restrict__ Whh,
                           const float* __restrict__ bsrc, u16* __restrict__ Wf,
                           float* __restrict__ bf, int DIN) {
  const int K = DIN + 512;
  const int bx = blockIdx.x;  // 4096
  const int dir = bx >> 11, r = bx & 2047;
  const int g = (r >> 4) & 3, j = ((r >> 6) << 4) | (r & 15);
  const int orig = g * 512 + j;
  const float* wi = Wih + ((size_t)dir * 2048 + orig) * DIN;
  const float* wh = Whh + ((size_t)dir * 2048 + orig) * 512;
  u16* dst = Wf + ((size_t)dir * 2048 + r) * K;
  for (int k = threadIdx.x; k < K; k += 256)
    dst[k] = f2bf(k < DIN ? wi[k] : wh[k - DIN]);
  if (threadIdx.x == 0) bf[dir * 2048 + r] = bsrc[dir * 2048 + orig];
}

__global__ void k_pack_dec(const float* __restrict__ Wih, const float* __restrict__ Whh,
                           const float* __restrict__ bsrc, u16* __restrict__ Wf,
                           float* __restrict__ bf, int KIN) {
  const int K = KIN + 1024;
  const int r = blockIdx.x;  // 4096
  const int g = (r >> 4) & 3, j = ((r >> 6) << 4) | (r & 15);
  const int orig = g * 1024 + j;
  const float* wi = Wih + (size_t)orig * KIN;
  const float* wh = Whh + (size_t)orig * 1024;
  u16* dst = Wf + (size_t)r * K;
  for (int k = threadIdx.x; k < K; k += 256)
    dst[k] = f2bf(k < KIN ? wi[k] : wh[k - KIN]);
  if (threadIdx.x == 0) bf[r] = bsrc[orig];
}

// WQ[a][c][d] = attnW_a[d][c]  (transposed, bf16)
__global__ void k_pack_attnT(const float* __restrict__ w1, const float* __restrict__ w2,
                             const float* __restrict__ w3, u16* __restrict__ WQ) {
  const int a = blockIdx.x >> 10, tix = blockIdx.x & 1023;
  const int ti = tix >> 5, tj = tix & 31;  // d-tile, c-tile
  const float* Wsrc = a == 0 ? w1 : (a == 1 ? w2 : w3);
  __shared__ float tl[32][33];
  const int r = threadIdx.x >> 3, c4 = (threadIdx.x & 7) * 4;
  const float* src = Wsrc + (size_t)(ti * 32 + r) * 1024 + tj * 32 + c4;
#pragma unroll
  for (int k = 0; k < 4; ++k) tl[r][c4 + k] = src[k];
  __syncthreads();
  const int cl = threadIdx.x >> 3, d4 = (threadIdx.x & 7) * 4;
  ushort4 u;
  u.x = f2bf(tl[d4 + 0][cl]); u.y = f2bf(tl[d4 + 1][cl]);
  u.z = f2bf(tl[d4 + 2][cl]); u.w = f2bf(tl[d4 + 3][cl]);
  *(ushort4*)(WQ + ((size_t)a << 20) + (size_t)(tj * 32 + cl) * 1024 + ti * 32 + d4) = u;
}

// ---------------- persistent bidirectional LSTM layer ----------------
// grid 128: dir(2) x Mtile(2x64) x Ntile(32x64 gate-rows = 16 h-dims)
__global__ __launch_bounds__(256, 1) void k_enc(
    const u16* __restrict__ in, int DIN,
    const u16* __restrict__ Wf, const float* __restrict__ bias,
    u16* __restrict__ hst, u16* __restrict__ outp, u32* __restrict__ flags) {
  const int K = DIN + 512;
  const int wg = blockIdx.x;
  const int dir = wg >> 6, mt = (wg >> 5) & 1, nt = wg & 31;
  const int m0 = mt * 64, r0 = nt * 64, j0 = nt * 16;
  const int tid = threadIdx.x, w = tid >> 6, lane = tid & 63;
  const int l15 = lane & 15, qd = lane >> 4;

  const u16* Wd = Wf + (size_t)dir * 2048 * (size_t)K;
  const int wrow = r0 + w * 16 + l15;
  const u16* wbase = Wd + (size_t)wrow * K + qd * 8;
  const float bsv = bias[dir * 2048 + wrow];

  size_t aoff_in[4], aoff_h[4];
#pragma unroll
  for (int mi = 0; mi < 4; ++mi) {
    int row = m0 + mi * 16 + l15;
    aoff_in[mi] = (size_t)row * 256 * (size_t)DIN;
    aoff_h[mi] = (size_t)row * 512;
  }

  __shared__ float glds[4][64][17];
  float cst[4] = {0.f, 0.f, 0.f, 0.f};
  const int pm = tid & 63, jb = (tid >> 6) << 2;
  u32 bt = 1;

  for (int t = 0; t < 256; ++t) {
    const int tt = dir ? (255 - t) : t;
    const int pb = t & 1;
    v4f acc[4];
#pragma unroll
    for (int mi = 0; mi < 4; ++mi) acc[mi] = (v4f){0.f, 0.f, 0.f, 0.f};

    const u16* inb = in + (size_t)tt * DIN + qd * 8;
    for (int kk = 0; kk < DIN; kk += 32) {
      v8s bf = ld8(wbase + kk);
#pragma unroll
      for (int mi = 0; mi < 4; ++mi)
        acc[mi] = mfma16(ld8(inb + aoff_in[mi] + kk), bf, acc[mi]);
    }
    const u16* hrd = hst + ((size_t)(dir * 2 + pb) * 128) * 512 + qd * 8;
    const u16* wb2 = wbase + DIN;
#pragma unroll 2
    for (int kk = 0; kk < 512; kk += 32) {
      v8s bf = ld8(wb2 + kk);
#pragma unroll
      for (int mi = 0; mi < 4; ++mi)
        acc[mi] = mfma16(ld8(hrd + aoff_h[mi] + kk), bf, acc[mi]);
    }
#pragma unroll
    for (int mi = 0; mi < 4; ++mi)
#pragma unroll
      for (int r = 0; r < 4; ++r)
        glds[w][mi * 16 + qd * 4 + r][l15] = acc[mi][r] + bsv;
    __syncthreads();

    ushort4 hv;
    {
      float h4[4];
#pragma unroll
      for (int jj = 0; jj < 4; ++jj) {
        int j = jb + jj;
        float gi = glds[0][pm][j], gf = glds[1][pm][j];
        float gg = glds[2][pm][j], go = glds[3][pm][j];
        float cc = sigm(gf) * cst[jj] + sigm(gi) * tanhf(gg);
        cst[jj] = cc;
        h4[jj] = sigm(go) * tanhf(cc);
      }
      hv.x = f2bf(h4[0]); hv.y = f2bf(h4[1]); hv.z = f2bf(h4[2]); hv.w = f2bf(h4[3]);
    }
    *(ushort4*)(hst + ((size_t)(dir * 2 + (pb ^ 1)) * 128 + m0 + pm) * 512 + j0 + jb) = hv;
    *(ushort4*)(outp + ((size_t)(m0 + pm) * 256 + tt) * 1024 + dir * 512 + j0 + jb) = hv;
    gbar(flags, 128, wg, bt++);
  }
}

// ---------------- persistent decoder ----------------
struct DecArgs {
  const float *x, *ab1, *ab2, *ab3, *outb;
  float* dout;
  const u16 *eo, *wq, *wout, *wd1, *wd2, *wd3;
  const float *bd1, *bd2, *bd3;
  u16 *qp, *hd, *ad1, *ad2, *ad3;
  float *s0, *cd, *pctx, *pml, *cp;
  u32* flags;
};

struct DecSmem {
  u16 e[32][1032];       // padded rows: bank-conflict-free B-frags
  float sbuf[4][16][4];
  float scl[32][4];
  float wl[32][4];
  float mml[3], lll[3], alpha[3], s0l[3];
};

__global__ __launch_bounds__(256, 1) void k_dec(DecArgs A) {
  const int wg = blockIdx.x, tid = threadIdx.x;
  const int w = tid >> 6, lane = tid & 63, l15 = lane & 15, qd = lane >> 4;
  __shared__ DecSmem sm;

  u32 bt = 1;
  const u16* WDs[3] = {A.wd1, A.wd2, A.wd3};
  const float* BDs[3] = {A.bd1, A.bd2, A.bd3};
  u16* ADs[3] = {A.ad1, A.ad2, A.ad3};
  const int KCs[3] = {2112, 3072, 3072};

  for (int t = 0; t <= 60; ++t) {
    const int p = t & 1;
    // ---------------- P1: q projections, y/prev, s0 dots ----------------
    if (wg < 192) {
      const int a = wg >> 6, rr = wg & 63, mt = rr >> 5, nt = rr & 31;
      const int mb = mt * 64 + (w >> 1) * 32;
      const int nc0 = nt * 32 + (w & 1) * 16;
      const u16* Ah = A.hd + ((size_t)(a * 2 + p) * 128) * 1024;
      const u16* Bw = A.wq + ((size_t)a << 20) + (size_t)(nc0 + l15) * 1024 + qd * 8;
      v4f acc0 = (v4f){0.f, 0.f, 0.f, 0.f}, acc1 = acc0;
      const u16* Ab0 = Ah + (size_t)(mb + l15) * 1024 + qd * 8;
      const u16* Ab1 = Ah + (size_t)(mb + 16 + l15) * 1024 + qd * 8;
      for (int kk = 0; kk < 1024; kk += 32) {
        v8s bf = ld8(Bw + kk);
        acc0 = mfma16(ld8(Ab0 + kk), bf, acc0);
        acc1 = mfma16(ld8(Ab1 + kk), bf, acc1);
      }
      const int cc = nc0 + l15;
#pragma unroll
      for (int r = 0; r < 4; ++r) {
        int m = mb + qd * 4 + r;
        A.qp[(size_t)m * 16384 + a * 1024 + cc] = f2bf(acc0[r]);
        A.qp[(size_t)(m + 16) * 16384 + a * 1024 + cc] = f2bf(acc1[r]);
      }
    } else if (wg < 196) {
      const int mt = wg - 192;
      if (t == 0) {
        int base = (mt * 256 + tid) * 8;
        int b = base >> 6, o = base & 63;
#pragma unroll
        for (int k2 = 0; k2 < 8; ++k2)
          A.ad1[(size_t)b * 2112 + 1024 + o + k2] =
              f2bf(A.x[(size_t)b * 16384 + 255 * 64 + o + k2]);
      } else {
        const int mb = mt * 32;
        const u16* Ah = A.hd + ((size_t)(2 * 2 + p) * 128) * 1024;
        const u16* Bw = A.wout + (size_t)(w * 16 + l15) * 1024 + qd * 8;
        v4f acc0 = (v4f){0.f, 0.f, 0.f, 0.f}, acc1 = acc0;
        const u16* Ab0 = Ah + (size_t)(mb + l15) * 1024 + qd * 8;
        const u16* Ab1 = Ah + (size_t)(mb + 16 + l15) * 1024 + qd * 8;
        for (int kk = 0; kk < 1024; kk += 32) {
          v8s bf = ld8(Bw + kk);
          acc0 = mfma16(ld8(Ab0 + kk), bf, acc0);
          acc1 = mfma16(ld8(Ab1 + kk), bf, acc1);
        }
        const int o = w * 16 + l15;
        const float bo = A.outb[o];
#pragma unroll
        for (int r = 0; r < 4; ++r) {
          int m = mb + qd * 4 + r;
          float y0 = acc0[r] + bo, y1 = acc1[r] + bo;
          A.dout[(size_t)m * 3840 + (t - 1) * 64 + o] = y0;
          A.dout[(size_t)(m + 16) * 3840 + (t - 1) * 64 + o] = y1;
          A.ad1[(size_t)m * 2112 + 1024 + o] = f2bf(y0);
          A.ad1[(size_t)(m + 16) * 2112 + 1024 + o] = f2bf(y1);
        }
      }
    } else if (wg < 199) {
      const int a = wg - 196;
      if (tid < 128) {
        const u16* hr = A.hd + ((size_t)(a * 2 + p) * 128 + tid) * 1024;
        const float* ab = (a == 0) ? A.ab1 : (a == 1 ? A.ab2 : A.ab3);
        float s = 0.f;
        for (int k = 0; k < 1024; k += 4)
          s += bf2f(hr[k]) * ab[k] + bf2f(hr[k + 1]) * ab[k + 1] +
               bf2f(hr[k + 2]) * ab[k + 2] + bf2f(hr[k + 3]) * ab[k + 3];
        A.s0[a * 128 + tid] = s;
      }
    }
    gbar(A.flags, 256, wg, bt++);
    if (t == 60) break;

    // ---------------- P2: fused 3-way flash attention over enc_out ----------------
    {
      const int b = wg >> 1, shf = wg & 1;
      if (tid < 3) {
        sm.mml[tid] = -3e38f;
        sm.lll[tid] = 0.f;
        sm.s0l[tid] = A.s0[tid * 128 + b];
      }
      v4f cx0 = (v4f){0.f, 0.f, 0.f, 0.f}, cx1 = cx0, cx2 = cx0;
      const int c0 = tid * 4;
      __syncthreads();
      for (int sc4 = 0; sc4 < 4; ++sc4) {
        const int sg = shf * 128 + sc4 * 32;
        const u16* ech = A.eo + ((size_t)b * 256 + sg) * 1024;
        {
          const int row2 = tid >> 7, within = tid & 127;
          for (int pr = 0; pr < 16; ++pr) {
            int row = pr * 2 + row2;
            *(uint4*)&sm.e[row][within * 8] =
                *(const uint4*)(ech + (size_t)row * 1024 + within * 8);
          }
        }
        __syncthreads();
        {
          const int ssub = (w >> 1) * 16, kh = (w & 1) * 512;
          v4f sa = (v4f){0.f, 0.f, 0.f, 0.f};
          const u16* qb = A.qp + (size_t)b * 16384 + (size_t)l15 * 1024 + kh + qd * 8;
          const u16* eb = &sm.e[ssub + l15][kh + qd * 8];
          for (int kk = 0; kk < 512; kk += 32)
            sa = mfma16(ld8(qb + kk), ld8(eb + kk), sa);
          if (lane < 16) *(v4f*)&sm.sbuf[w][lane][0] = sa;
        }
        __syncthreads();
        if (tid < 32) {
          const int wp = (tid >> 4) * 2, sl = tid & 15;
#pragma unroll
          for (int a = 0; a < 3; ++a)
            sm.scl[tid][a] = sm.sbuf[wp][sl][a] + sm.sbuf[wp + 1][sl][a] + sm.s0l[a];
        }
        __syncthreads();
        if (tid < 3) {
          float cm = -3e38f;
          for (int s = 0; s < 32; ++s) cm = fmaxf(cm, sm.scl[s][tid]);
          float nm = fmaxf(sm.mml[tid], cm);
          sm.alpha[tid] = __expf(sm.mml[tid] - nm);
          sm.mml[tid] = nm;
        }
        __syncthreads();
        if (tid < 32) {
#pragma unroll
          for (int a = 0; a < 3; ++a)
            sm.wl[tid][a] = __expf(sm.scl[tid][a] - sm.mml[a]);
        }
        __syncthreads();
        if (tid < 3) {
          float s = 0.f;
          for (int i = 0; i < 32; ++i) s += sm.wl[i][tid];
          sm.lll[tid] = sm.lll[tid] * sm.alpha[tid] + s;
        }
        const float a0 = sm.alpha[0], a1 = sm.alpha[1], a2 = sm.alpha[2];
#pragma unroll
        for (int k2 = 0; k2 < 4; ++k2) { cx0[k2] *= a0; cx1[k2] *= a1; cx2[k2] *= a2; }
        for (int s = 0; s < 32; ++s) {
          v4f wv = *(v4f*)&sm.wl[s][0];
          ushort4 ev = *(ushort4*)&sm.e[s][c0];
          float e0 = bf2f(ev.x), e1 = bf2f(ev.y), e2 = bf2f(ev.z), e3 = bf2f(ev.w);
          cx0[0] += wv[0] * e0; cx0[1] += wv[0] * e1; cx0[2] += wv[0] * e2; cx0[3] += wv[0] * e3;
          cx1[0] += wv[1] * e0; cx1[1] += wv[1] * e1; cx1[2] += wv[1] * e2; cx1[3] += wv[1] * e3;
          cx2[0] += wv[2] * e0; cx2[1] += wv[2] * e1; cx2[2] += wv[2] * e2; cx2[3] += wv[2] * e3;
        }
        __syncthreads();
      }
      *(v4f*)(A.pctx + ((size_t)(shf * 3 + 0) * 128 + b) * 1024 + c0) = cx0;
      *(v4f*)(A.pctx + ((size_t)(shf * 3 + 1) * 128 + b) * 1024 + c0) = cx1;
      *(v4f*)(A.pctx + ((size_t)(shf * 3 + 2) * 128 + b) * 1024 + c0) = cx2;
      if (tid < 3) {
        A.pml[((size_t)(shf * 3 + tid) * 128 + b) * 2 + 0] = sm.mml[tid];
        A.pml[((size_t)(shf * 3 + tid) * 128 + b) * 2 + 1] = sm.lll[tid];
      }
    }
    gbar(A.flags, 256, wg, bt++);

    // ---------------- P3: combine partials -> ctx into A-staging; copy h_old segs ----------------
    if (wg < 128) {
      const int b = wg;
      const int c0 = tid * 4;
#pragma unroll
      for (int a = 0; a < 3; ++a) {
        float m0v = A.pml[((size_t)(0 * 3 + a) * 128 + b) * 2 + 0];
        float l0v = A.pml[((size_t)(0 * 3 + a) * 128 + b) * 2 + 1];
        float m1v = A.pml[((size_t)(1 * 3 + a) * 128 + b) * 2 + 0];
        float l1v = A.pml[((size_t)(1 * 3 + a) * 128 + b) * 2 + 1];
        float M = fmaxf(m0v, m1v);
        float w0 = __expf(m0v - M), w1 = __expf(m1v - M);
        float inv = 1.0f / (l0v * w0 + l1v * w1);
        const float* p0 = A.pctx + ((size_t)(0 * 3 + a) * 128 + b) * 1024;
        const float* p1 = A.pctx + ((size_t)(1 * 3 + a) * 128 + b) * 1024;
        v4f v0 = *(const v4f*)(p0 + c0), v1 = *(const v4f*)(p1 + c0);
        ushort4 u;
        u.x = f2bf((v0[0] * w0 + v1[0] * w1) * inv);
        u.y = f2bf((v0[1] * w0 + v1[1] * w1) * inv);
        u.z = f2bf((v0[2] * w0 + v1[2] * w1) * inv);
        u.w = f2bf((v0[3] * w0 + v1[3] * w1) * inv);
        *(ushort4*)(ADs[a] + (size_t)b * KCs[a] + c0) = u;
      }
    } else {
      const int b = wg - 128;
      const int c0 = tid * 4;
      const u16* h1 = A.hd + ((size_t)(0 * 2 + p) * 128 + b) * 1024;
      const u16* h2 = A.hd + ((size_t)(1 * 2 + p) * 128 + b) * 1024;
      const u16* h3 = A.hd + ((size_t)(2 * 2 + p) * 128 + b) * 1024;
      *(ushort4*)(A.ad1 + (size_t)b * 2112 + 1088 + c0) = *(const ushort4*)(h1 + c0);
      *(ushort4*)(A.ad2 + (size_t)b * 3072 + 2048 + c0) = *(const ushort4*)(h2 + c0);
      *(ushort4*)(A.ad3 + (size_t)b * 3072 + 2048 + c0) = *(const ushort4*)(h3 + c0);
    }
    gbar(A.flags, 256, wg, bt++);

    // ---------------- cells 1..3: K-split GEMM then pointwise ----------------
#pragma unroll
    for (int ci = 0; ci < 3; ++ci) {
      const int Kc = KCs[ci];
      const u16* Wc = WDs[ci];
      const u16* Ac = ADs[ci];
      {
        const int kp = wg >> 7, mt = (wg >> 6) & 1, nt = wg & 63;
        const int m0c = mt * 64;
        const int wrow = nt * 64 + w * 16 + l15;
        const int Kh = Kc >> 1, ks = kp * Kh;
        const u16* wb = Wc + (size_t)wrow * Kc + ks + qd * 8;
        v4f acc[4];
#pragma unroll
        for (int mi = 0; mi < 4; ++mi) acc[mi] = (v4f){0.f, 0.f, 0.f, 0.f};
        size_t ao[4];
#pragma unroll
        for (int mi = 0; mi < 4; ++mi)
          ao[mi] = (size_t)(m0c + mi * 16 + l15) * Kc + ks + qd * 8;
        for (int kk = 0; kk < Kh; kk += 32) {
          v8s bf = ld8(wb + kk);
#pragma unroll
          for (int mi = 0; mi < 4; ++mi)
            acc[mi] = mfma16(ld8(Ac + ao[mi] + kk), bf, acc[mi]);
        }
        float* cpb = A.cp + (size_t)kp * 128 * 4096;
#pragma unroll
        for (int mi = 0; mi < 4; ++mi)
#pragma unroll
          for (int r = 0; r < 4; ++r)
            cpb[(size_t)(m0c + mi * 16 + qd * 4 + r) * 4096 + wrow] = acc[mi][r];
      }
      gbar(A.flags, 256, wg, bt++);
      {
        const float* bdc = BDs[ci];
        const int idx = (wg * 256 + tid) * 2;
        const int mm = idx >> 10;
        const int j0v = idx & 1023;
        float* cptr = A.cd + ((size_t)ci * 128 + mm) * 1024;
        u16* hdw = A.hd + ((size_t)(ci * 2 + (p ^ 1)) * 128 + mm) * 1024;
        u16* adn = (ci < 2) ? (ADs[ci + 1] + (size_t)mm * 3072 + 1024) : (u16*)0;
        const float* cp0 = A.cp + (size_t)mm * 4096;
        const float* cp1 = A.cp + (size_t)(128 + mm) * 4096;
#pragma unroll
        for (int u2 = 0; u2 < 2; ++u2) {
          const int j = j0v + u2;
          const int rb = ((j >> 4) << 6) | (j & 15);
          float gi = cp0[rb] + cp1[rb] + bdc[rb];
          float gf = cp0[rb + 16] + cp1[rb + 16] + bdc[rb + 16];
          float gg = cp0[rb + 32] + cp1[rb + 32] + bdc[rb + 32];
          float go = cp0[rb + 48] + cp1[rb + 48] + bdc[rb + 48];
          float cv = cptr[j];
          cv = sigm(gf) * cv + sigm(gi) * tanhf(gg);
          cptr[j] = cv;
          u16 hb = f2bf(sigm(go) * tanhf(cv));
          hdw[j] = hb;
          if (adn) adn[j] = hb;
        }
      }
      gbar(A.flags, 256, wg, bt++);
    }
  }
}

// ---------------- host ----------------
extern "C" void kernel_launch(void* const* d_in, const int* in_sizes, int n_in,
                              void* d_out, int out_size, void* d_ws, size_t ws_size,
                              hipStream_t stream) {
  char* ws = (char*)d_ws;
  size_t off = 0;
  auto alc = [&](size_t bytes) -> char* {
    char* pp = ws + off;
    off += (bytes + 255) & ~(size_t)255;
    return pp;
  };
  u16* XB = (u16*)alc(2097152ull * 2);
  u16* WF0 = (u16*)alc(2359296ull * 2);
  float* BF0 = (float*)alc(4096ull * 4);
  u16* WF1 = (u16*)alc(6291456ull * 2);
  float* BF1 = (float*)alc(4096ull * 4);
  u16* H0 = (u16*)alc(33554432ull * 2);
  u16* EO = (u16*)alc(33554432ull * 2);
  u16* HS0 = (u16*)alc(262144ull * 2);
  u16* HS1 = (u16*)alc(262144ull * 2);
  u16* WQ = (u16*)alc(3145728ull * 2);
  u16* WOUT = (u16*)alc(65536ull * 2);
  u16* WD1 = (u16*)alc(8650752ull * 2);
  float* BD1 = (float*)alc(4096ull * 4);
  u16* WD2 = (u16*)alc(12582912ull * 2);
  float* BD2 = (float*)alc(4096ull * 4);
  u16* WD3 = (u16*)alc(12582912ull * 2);
  float* BD3 = (float*)alc(4096ull * 4);
  u16* QP = (u16*)alc(2097152ull * 2);
  float* S0 = (float*)alc(384ull * 4);
  u16* HD = (u16*)alc(786432ull * 2);
  float* CD = (float*)alc(393216ull * 4);
  float* PCTX = (float*)alc(786432ull * 4);
  float* PML = (float*)alc(1536ull * 4);
  u16* AD1 = (u16*)alc(270336ull * 2);
  u16* AD2 = (u16*)alc(393216ull * 2);
  u16* AD3 = (u16*)alc(393216ull * 2);
  float* CP = (float*)alc(1048576ull * 4);
  u32* FLAGS = (u32*)alc(1536ull * 4);

  // zero state buffers (ws is poisoned before every call)
  k_zero<<<2, 256, 0, stream>>>((uint4*)FLAGS, 384);
  k_zero<<<1024, 256, 0, stream>>>((uint4*)QP, 262144);
  k_zero<<<128, 256, 0, stream>>>((uint4*)HS0, 32768);
  k_zero<<<128, 256, 0, stream>>>((uint4*)HS1, 32768);
  k_zero<<<384, 256, 0, stream>>>((uint4*)HD, 98304);
  k_zero<<<384, 256, 0, stream>>>((uint4*)CD, 98304);

  // pack weights / inputs to bf16
  k_cvt<<<2048, 256, 0, stream>>>((const float*)d_in[0], XB, 2097152);
  k_cvt<<<64, 256, 0, stream>>>((const float*)d_in[22], WOUT, 65536);
  k_pack_enc<<<4096, 256, 0, stream>>>((const float*)d_in[1], (const float*)d_in[2],
                                       (const float*)d_in[3], WF0, BF0, 64);
  k_pack_enc<<<4096, 256, 0, stream>>>((const float*)d_in[4], (const float*)d_in[5],
                                       (const float*)d_in[6], WF1, BF1, 1024);
  k_pack_attnT<<<3072, 256, 0, stream>>>((const float*)d_in[7], (const float*)d_in[9],
                                         (const float*)d_in[11], WQ);
  k_pack_dec<<<4096, 256, 0, stream>>>((const float*)d_in[13], (const float*)d_in[14],
                                       (const float*)d_in[15], WD1, BD1, 1088);
  k_pack_dec<<<4096, 256, 0, stream>>>((const float*)d_in[16], (const float*)d_in[17],
                                       (const float*)d_in[18], WD2, BD2, 2048);
  k_pack_dec<<<4096, 256, 0, stream>>>((const float*)d_in[19], (const float*)d_in[20],
                                       (const float*)d_in[21], WD3, BD3, 2048);

  // encoder layers (persistent, 128 WGs each)
  k_enc<<<128, 256, 0, stream>>>(XB, 64, WF0, BF0, HS0, H0, FLAGS);
  k_enc<<<128, 256, 0, stream>>>(H0, 1024, WF1, BF1, HS1, EO, FLAGS + 512);

  // decoder (persistent, 256 WGs)
  DecArgs da;
  da.x = (const float*)d_in[0];
  da.ab1 = (const float*)d_in[8];
  da.ab2 = (const float*)d_in[10];
  da.ab3 = (const float*)d_in[12];
  da.outb = (const float*)d_in[23];
  da.dout = (float*)d_out;
  da.eo = EO; da.wq = WQ; da.wout = WOUT;
  da.wd1 = WD1; da.wd2 = WD2; da.wd3 = WD3;
  da.bd1 = BD1; da.bd2 = BD2; da.bd3 = BD3;
  da.qp = QP; da.hd = HD; da.ad1 = AD1; da.ad2 = AD2; da.ad3 = AD3;
  da.s0 = S0; da.cd = CD; da.pctx = PCTX; da.pml = PML; da.cp = CP;
  da.flags = FLAGS + 1024;
  k_dec<<<256, 256, 0, stream>>>(da);
}

// Round 2
// 26781.940 us; speedup vs baseline: 1.3798x; 1.3798x over previous
//
#include <hip/hip_runtime.h>

typedef unsigned short u16;
typedef unsigned int u32;
typedef short v8s __attribute__((ext_vector_type(8)));
typedef float v4f __attribute__((ext_vector_type(4)));

#define DEV static __device__ __forceinline__

DEV float bf2f(u16 u) { union { u32 i; float f; } v; v.i = ((u32)u) << 16; return v.f; }
DEV u16 f2bf(float f) {
  union { float f; u32 i; } v; v.f = f;
  u32 i = v.i + 0x7FFFu + ((v.i >> 16) & 1u);
  return (u16)(i >> 16);
}
DEV float sigm(float x) { return 1.0f / (1.0f + __expf(-x)); }
DEV v4f mfma16(v8s a, v8s b, v4f c) {
  return __builtin_amdgcn_mfma_f32_16x16x32_bf16(a, b, c, 0, 0, 0);
}
DEV v8s ld8(const u16* p) { return *(const v8s*)p; }

// ---------------- grid barrier (flag array, agent scope) ----------------
DEV void gbar(u32* flags, int nwg, int wg, u32 tgt) {
  __syncthreads();
  if (threadIdx.x < 64) {
    if (threadIdx.x == 0) {
      __threadfence();
      __hip_atomic_store(flags + wg, tgt, __ATOMIC_RELEASE, __HIP_MEMORY_SCOPE_AGENT);
    }
    const int lane = threadIdx.x;
    for (;;) {
      bool ok = true;
      for (int i = lane; i < nwg; i += 64) {
        u32 v = __hip_atomic_load(flags + i, __ATOMIC_RELAXED, __HIP_MEMORY_SCOPE_AGENT);
        ok &= (v >= tgt);
      }
      if (__ballot((int)ok) == ~0ull) break;
      __builtin_amdgcn_s_sleep(1);
    }
    __threadfence();
  }
  __syncthreads();
}

// ---------------- small utility kernels ----------------
__global__ void k_zero(uint4* p, int n) {
  int i = blockIdx.x * 256 + threadIdx.x;
  if (i < n) p[i] = make_uint4(0, 0, 0, 0);
}

__global__ void k_cvt(const float* __restrict__ s, u16* __restrict__ d, int n) {
  int i = (blockIdx.x * 256 + threadIdx.x) * 4;
  if (i < n) {
    float4 v = *(const float4*)(s + i);
    ushort4 u;
    u.x = f2bf(v.x); u.y = f2bf(v.y); u.z = f2bf(v.z); u.w = f2bf(v.w);
    *(ushort4*)(d + i) = u;
  }
}

// fused [Wih|Whh], 4-granular gate interleave:
// packed row r: g=(r>>2)&3, j=((r>>4)<<2)|(r&3) -> orig = g*H + j
__global__ void k_pack_enc(const float* __restrict__ Wih, const float* __restrict__ Whh,
                           const float* __restrict__ bsrc, u16* __restrict__ Wf,
                           float* __restrict__ bf, int DIN) {
  const int K = DIN + 512;
  const int bx = blockIdx.x;  // 4096
  const int dir = bx >> 11, r = bx & 2047;
  const int g = (r >> 2) & 3, j = ((r >> 4) << 2) | (r & 3);
  const int orig = g * 512 + j;
  const float* wi = Wih + ((size_t)dir * 2048 + orig) * DIN;
  const float* wh = Whh + ((size_t)dir * 2048 + orig) * 512;
  u16* dst = Wf + ((size_t)dir * 2048 + r) * K;
  for (int k = threadIdx.x; k < K; k += 256)
    dst[k] = f2bf(k < DIN ? wi[k] : wh[k - DIN]);
  if (threadIdx.x == 0) bf[dir * 2048 + r] = bsrc[dir * 2048 + orig];
}

__global__ void k_pack_dec(const float* __restrict__ Wih, const float* __restrict__ Whh,
                           const float* __restrict__ bsrc, u16* __restrict__ Wf,
                           float* __restrict__ bf, int KIN) {
  const int K = KIN + 1024;
  const int r = blockIdx.x;  // 4096
  const int g = (r >> 2) & 3, j = ((r >> 4) << 2) | (r & 3);
  const int orig = g * 1024 + j;
  const float* wi = Wih + (size_t)orig * KIN;
  const float* wh = Whh + (size_t)orig * 1024;
  u16* dst = Wf + (size_t)r * K;
  for (int k = threadIdx.x; k < K; k += 256)
    dst[k] = f2bf(k < KIN ? wi[k] : wh[k - KIN]);
  if (threadIdx.x == 0) bf[r] = bsrc[orig];
}

// WQ[a][c][d] = attnW_a[d][c]  (transposed, bf16)
__global__ void k_pack_attnT(const float* __restrict__ w1, const float* __restrict__ w2,
                             const float* __restrict__ w3, u16* __restrict__ WQ) {
  const int a = blockIdx.x >> 10, tix = blockIdx.x & 1023;
  const int ti = tix >> 5, tj = tix & 31;
  const float* Wsrc = a == 0 ? w1 : (a == 1 ? w2 : w3);
  __shared__ float tl[32][33];
  const int r = threadIdx.x >> 3, c4 = (threadIdx.x & 7) * 4;
  const float* src = Wsrc + (size_t)(ti * 32 + r) * 1024 + tj * 32 + c4;
#pragma unroll
  for (int k = 0; k < 4; ++k) tl[r][c4 + k] = src[k];
  __syncthreads();
  const int cl = threadIdx.x >> 3, d4 = (threadIdx.x & 7) * 4;
  ushort4 u;
  u.x = f2bf(tl[d4 + 0][cl]); u.y = f2bf(tl[d4 + 1][cl]);
  u.z = f2bf(tl[d4 + 2][cl]); u.w = f2bf(tl[d4 + 3][cl]);
  *(ushort4*)(WQ + ((size_t)a << 20) + (size_t)(tj * 32 + cl) * 1024 + ti * 32 + d4) = u;
}

// ---------------- persistent bidirectional LSTM layer ----------------
// grid 256 x 512thr: dir(2) x Mtile(2x64) x Ntile(64 x 32 gate-rows = 8 h-dims)
// Weights held in LDS in MFMA-fragment layout. 1 sub-barrier (64 WGs) per step.
#define ENC_KMAX 48  // (1024+512)/32

__global__ __launch_bounds__(512, 1) void k_enc(
    const u16* __restrict__ in, int DIN,
    const u16* __restrict__ Wf, const float* __restrict__ bias,
    u16* __restrict__ hst, u16* __restrict__ outp, u32* __restrict__ flags) {
  const int K = DIN + 512;
  const int wg = blockIdx.x;
  const int dir = wg >> 7, mt = (wg >> 6) & 1, nt = wg & 63;
  const int m0 = mt * 64, r0 = nt * 32, j0 = nt * 8;
  const int tid = threadIdx.x, w = tid >> 6, lane = tid & 63;
  const int l15 = lane & 15, qd = lane >> 4;
  const int mh = w >> 1, nq = w & 1;

  __shared__ u16 wlds[ENC_KMAX * 1024];  // [kkb][nq][64 lanes][8]
  __shared__ float glds[64][33];

  // stage weights -> LDS fragment layout
  {
    const u16* Wd = Wf + ((size_t)dir * 2048 + r0) * K;
    const int K8 = K >> 3;
    for (int idx = tid; idx < 32 * K8; idx += 512) {
      int row = idx & 31, c8 = idx >> 5;
      uint4 v = *(const uint4*)(Wd + (size_t)row * K + c8 * 8);
      int kkb = c8 >> 2, lq = ((c8 & 3) << 4) | (row & 15), snq = row >> 4;
      *(uint4*)(wlds + (((kkb * 2 + snq) * 64 + lq) << 3)) = v;
    }
  }
  // pointwise mapping + bias regs
  const int pm = tid >> 3, pj = tid & 7, pblk = pj >> 2, pjl = pj & 3;
  float bw[4];
#pragma unroll
  for (int g = 0; g < 4; ++g)
    bw[g] = bias[dir * 2048 + r0 + pblk * 16 + g * 4 + pjl];
  float cst = 0.f;
  __syncthreads();

  const int arow = m0 + mh * 16 + l15;
  const u16* xbase = in + (size_t)arow * 256 * DIN + qd * 8;
  u32* gfl = flags + (dir * 2 + mt) * 64;
  u32 bt = 1;

  for (int t = 0; t < 256; ++t) {
    const int tt = dir ? (255 - t) : t;
    const int pb = t & 1;
    v4f acc = (v4f){0.f, 0.f, 0.f, 0.f};
    const u16* xp = xbase + (size_t)tt * DIN;
    const u16* wp = wlds + ((nq * 64 + lane) << 3);
    int kkb = 0;
#pragma unroll 4
    for (int kk = 0; kk < DIN; kk += 32, ++kkb)
      acc = mfma16(ld8(xp + kk), ld8(wp + (kkb << 10)), acc);
    const u16* hp = hst + ((size_t)((dir * 2 + pb) * 128 + arow)) * 512 + qd * 8;
#pragma unroll 4
    for (int kk = 0; kk < 512; kk += 32, ++kkb)
      acc = mfma16(ld8(hp + kk), ld8(wp + (kkb << 10)), acc);
#pragma unroll
    for (int r = 0; r < 4; ++r)
      glds[mh * 16 + qd * 4 + r][nq * 16 + l15] = acc[r];
    __syncthreads();
    // pointwise: thread = (m=pm, local hdim pj)
    {
      float gi = glds[pm][pblk * 16 + 0 * 4 + pjl] + bw[0];
      float gf = glds[pm][pblk * 16 + 1 * 4 + pjl] + bw[1];
      float gg = glds[pm][pblk * 16 + 2 * 4 + pjl] + bw[2];
      float go = glds[pm][pblk * 16 + 3 * 4 + pjl] + bw[3];
      float cc = sigm(gf) * cst + sigm(gi) * tanhf(gg);
      cst = cc;
      u16 hb = f2bf(sigm(go) * tanhf(cc));
      hst[((size_t)((dir * 2 + (pb ^ 1)) * 128 + m0 + pm)) * 512 + j0 + pj] = hb;
      outp[((size_t)(m0 + pm) * 256 + tt) * 1024 + dir * 512 + j0 + pj] = hb;
    }
    gbar(gfl, 64, nt, bt++);
  }
}

// ---------------- persistent decoder ----------------
struct DecArgs {
  const float *x, *outb;
  float* dout;
  const u16 *eo, *wq, *wout, *wd1, *wd2, *wd3;
  const float *bd1, *bd2, *bd3;
  u16 *qp, *hd, *ad1, *ad2, *ad3;
  u32* flags;
};

union DecSm {
  struct {
    u16 bfrag[96 * 512];   // [kkb][64 lanes][8]  96KB
    float glds[128][17];   // C staging  8.7KB
  } c;
  struct {
    float pctx[8][3072];   // per-wave PV partials  96KB
    float sbuf[8][16][4];
    float wl[32][4];
    float alpha[4];
    float lfin[4];
  } a;
};

__global__ __launch_bounds__(512, 1) void k_dec(DecArgs A) {
  const int wg = blockIdx.x, tid = threadIdx.x;
  const int w = tid >> 6, lane = tid & 63, l15 = lane & 15, qd = lane >> 4;
  __shared__ DecSm sm;
  u32 bt = 1;

  // cell pointwise mapping: thread = (m=cm_, jl=cjl); WG owns 16 gate rows = 4 hdims
  const int cm_ = tid >> 2, cjl = tid & 3;
  const float* BDs[3] = {A.bd1, A.bd2, A.bd3};
  float cbias[3][4];
#pragma unroll
  for (int ci = 0; ci < 3; ++ci)
#pragma unroll
    for (int g = 0; g < 4; ++g)
      cbias[ci][g] = BDs[ci][wg * 16 + g * 4 + cjl];
  float cstate[3] = {0.f, 0.f, 0.f};

  for (int t = 0; t <= 60; ++t) {
    const int p = t & 1;
    // ---------- P1: q projections (192 WGs), y-proj / prev seed (4 WGs) ----------
    if (wg < 192) {
      const int a = wg / 64, nc0 = (wg & 63) * 16;
      const u16* Ab = A.hd + (size_t)((a * 2 + p) * 128 + w * 16 + l15) * 1024 + qd * 8;
      const u16* Bw = A.wq + ((size_t)a << 20) + (size_t)(nc0 + l15) * 1024 + qd * 8;
      v4f acc = (v4f){0.f, 0.f, 0.f, 0.f};
#pragma unroll 4
      for (int kk = 0; kk < 1024; kk += 32)
        acc = mfma16(ld8(Ab + kk), ld8(Bw + kk), acc);
#pragma unroll
      for (int r = 0; r < 4; ++r)
        A.qp[(size_t)(w * 16 + qd * 4 + r) * 16384 + a * 1024 + nc0 + l15] = f2bf(acc[r]);
    } else if (wg < 196) {
      const int mt4 = wg - 192;
      if (t == 0) {
        int base = (mt4 * 512 + tid) * 4;  // 8192 = 128*64
        int b = base >> 6, o = base & 63;
        const float* xs = A.x + (size_t)b * 16384 + 255 * 64 + o;
        u16* dst = A.ad1 + (size_t)b * 2112 + 1024 + o;
#pragma unroll
        for (int k2 = 0; k2 < 4; ++k2) dst[k2] = f2bf(xs[k2]);
      } else {
        const int mb = mt4 * 32 + (w >> 2) * 16, nb = (w & 3) * 16;
        const u16* Ab = A.hd + (size_t)((2 * 2 + p) * 128 + mb + l15) * 1024 + qd * 8;
        const u16* Bw = A.wout + (size_t)(nb + l15) * 1024 + qd * 8;
        v4f acc = (v4f){0.f, 0.f, 0.f, 0.f};
#pragma unroll 4
        for (int kk = 0; kk < 1024; kk += 32)
          acc = mfma16(ld8(Ab + kk), ld8(Bw + kk), acc);
        const int o = nb + l15;
        const float bo = A.outb[o];
#pragma unroll
        for (int r = 0; r < 4; ++r) {
          int m = mb + qd * 4 + r;
          float y = acc[r] + bo;
          A.dout[(size_t)m * 3840 + (t - 1) * 64 + o] = y;
          A.ad1[(size_t)m * 2112 + 1024 + o] = f2bf(y);
        }
      }
    }
    gbar(A.flags, 256, wg, bt++);
    if (t == 60) break;

    // ---------- P2: fused 3-head flash attention (128 WGs) + h_old copies ----------
    if (wg < 128) {
      const int b = wg;
      const int sb = w >> 2, kq = w & 3;
      // preload q A-frags for this wave's K-quarter
      v8s qf[8];
      {
        const u16* qsrc = A.qp + (size_t)b * 16384 + (size_t)l15 * 1024 + kq * 256 + qd * 8;
#pragma unroll
        for (int i = 0; i < 8; ++i) qf[i] = ld8(qsrc + i * 32);
      }
      float pv[3][16];
#pragma unroll
      for (int aa = 0; aa < 3; ++aa)
#pragma unroll
        for (int i = 0; i < 16; ++i) pv[aa][i] = 0.f;
      float mml0 = -3e38f, mml1 = -3e38f, mml2 = -3e38f;
      float lll0 = 0.f, lll1 = 0.f, lll2 = 0.f;
      const u16* eob = A.eo + (size_t)b * 256 * 1024;

      for (int c = 0; c < 8; ++c) {
        const int sg = c * 32;
        // scores: wave (sb,kq): seq block sb*16, K-quarter kq (e read direct from global)
        {
          v4f sa = (v4f){0.f, 0.f, 0.f, 0.f};
          const u16* eb = eob + (size_t)(sg + sb * 16 + l15) * 1024 + kq * 256 + qd * 8;
#pragma unroll
          for (int i = 0; i < 8; ++i)
            sa = mfma16(qf[i], ld8(eb + i * 32), sa);
          if (lane < 16) *(v4f*)&sm.a.sbuf[w][lane][0] = sa;
        }
        __syncthreads();
        // online softmax over this 32-chunk (one half-wave)
        if (tid < 32) {
          const int s = tid, sbb = s >> 4, sl = s & 15;
          float sc0 = 0.f, sc1 = 0.f, sc2 = 0.f;
#pragma unroll
          for (int k = 0; k < 4; ++k) {
            const float* sp = &sm.a.sbuf[sbb * 4 + k][sl][0];
            sc0 += sp[0]; sc1 += sp[1]; sc2 += sp[2];
          }
          float c0 = sc0, c1 = sc1, c2 = sc2;
#pragma unroll
          for (int m = 16; m >= 1; m >>= 1) {
            c0 = fmaxf(c0, __shfl_xor(c0, m));
            c1 = fmaxf(c1, __shfl_xor(c1, m));
            c2 = fmaxf(c2, __shfl_xor(c2, m));
          }
          float n0 = fmaxf(mml0, c0), n1 = fmaxf(mml1, c1), n2 = fmaxf(mml2, c2);
          float a0 = __expf(mml0 - n0), a1 = __expf(mml1 - n1), a2 = __expf(mml2 - n2);
          mml0 = n0; mml1 = n1; mml2 = n2;
          float w0 = __expf(sc0 - n0), w1 = __expf(sc1 - n1), w2 = __expf(sc2 - n2);
          sm.a.wl[s][0] = w0; sm.a.wl[s][1] = w1; sm.a.wl[s][2] = w2;
          float t0 = w0, t1 = w1, t2 = w2;
#pragma unroll
          for (int m = 16; m >= 1; m >>= 1) {
            t0 += __shfl_xor(t0, m); t1 += __shfl_xor(t1, m); t2 += __shfl_xor(t2, m);
          }
          lll0 = lll0 * a0 + t0; lll1 = lll1 * a1 + t1; lll2 = lll2 * a2 + t2;
          if (s == 0) {
            sm.a.alpha[0] = a0; sm.a.alpha[1] = a1; sm.a.alpha[2] = a2;
            sm.a.lfin[0] = lll0; sm.a.lfin[1] = lll1; sm.a.lfin[2] = lll2;
          }
        }
        __syncthreads();
        // PV: wave w -> 4 seq rows, lane -> 16 dims (global e, L2-warm from scores)
        {
          const float a0 = sm.a.alpha[0], a1 = sm.a.alpha[1], a2 = sm.a.alpha[2];
#pragma unroll
          for (int i = 0; i < 16; ++i) { pv[0][i] *= a0; pv[1][i] *= a1; pv[2][i] *= a2; }
#pragma unroll
          for (int si = 0; si < 4; ++si) {
            const int s = w * 4 + si;
            const float w0 = sm.a.wl[s][0], w1 = sm.a.wl[s][1], w2 = sm.a.wl[s][2];
            const u16* ep = eob + (size_t)(sg + s) * 1024 + lane * 16;
            v8s e0 = ld8(ep), e1 = ld8(ep + 8);
#pragma unroll
            for (int i = 0; i < 8; ++i) {
              float ev = bf2f(((const u16*)&e0)[i]);
              pv[0][i] += w0 * ev; pv[1][i] += w1 * ev; pv[2][i] += w2 * ev;
            }
#pragma unroll
            for (int i = 0; i < 8; ++i) {
              float ev = bf2f(((const u16*)&e1)[i]);
              pv[0][8 + i] += w0 * ev; pv[1][8 + i] += w1 * ev; pv[2][8 + i] += w2 * ev;
            }
          }
        }
      }
      // dump per-wave partials, reduce, scale by 1/l, write ctx -> cell A-staging
      {
        float* pd = &sm.a.pctx[w][0];
#pragma unroll
        for (int aa = 0; aa < 3; ++aa) {
          float* q = pd + aa * 1024 + lane * 16;
#pragma unroll
          for (int i = 0; i < 16; ++i) q[i] = pv[aa][i];
        }
      }
      __syncthreads();
#pragma unroll
      for (int k = 0; k < 6; ++k) {
        const int aa = k >> 1;
        const int d = (k & 1) * 512 + tid;
        float s = 0.f;
#pragma unroll
        for (int ww = 0; ww < 8; ++ww) s += sm.a.pctx[ww][aa * 1024 + d];
        const float val = s / sm.a.lfin[aa];
        if (aa == 0) A.ad1[(size_t)b * 2112 + d] = f2bf(val);
        else if (aa == 1) A.ad2[(size_t)b * 3072 + d] = f2bf(val);
        else A.ad3[(size_t)b * 3072 + d] = f2bf(val);
      }
    } else {
      // WGs 128..255: copy h_old segments into cell A-staging
      const int b = wg - 128;
      const u16* h1 = A.hd + (size_t)((0 * 2 + p) * 128 + b) * 1024;
      const u16* h2 = A.hd + (size_t)((1 * 2 + p) * 128 + b) * 1024;
      const u16* h3 = A.hd + (size_t)((2 * 2 + p) * 128 + b) * 1024;
      if (tid < 128) {
        *(uint4*)(A.ad1 + (size_t)b * 2112 + 1088 + tid * 8) = *(const uint4*)(h1 + tid * 8);
      } else if (tid < 256) {
        int c8 = tid - 128;
        *(uint4*)(A.ad2 + (size_t)b * 3072 + 2048 + c8 * 8) = *(const uint4*)(h2 + c8 * 8);
      } else if (tid < 384) {
        int c8 = tid - 256;
        *(uint4*)(A.ad3 + (size_t)b * 3072 + 2048 + c8 * 8) = *(const uint4*)(h3 + c8 * 8);
      }
    }
    gbar(A.flags, 256, wg, bt++);

    // ---------- cells 1..3: fused GEMM (B in LDS frag layout) + pointwise ----------
#pragma unroll
    for (int ci = 0; ci < 3; ++ci) {
      const int Kc = (ci == 0) ? 2112 : 3072;
      const u16* Wc = (ci == 0 ? A.wd1 : ci == 1 ? A.wd2 : A.wd3) + (size_t)(wg * 16) * Kc;
      const u16* Ac = (ci == 0 ? A.ad1 : ci == 1 ? A.ad2 : A.ad3);
      // stage this WG's 16 weight rows into LDS fragment layout
      {
        const int K8 = Kc >> 3;
        const int row = tid & 15;
        for (int c8 = tid >> 4; c8 < K8; c8 += 32) {
          uint4 v = *(const uint4*)(Wc + (size_t)row * Kc + c8 * 8);
          int kkb = c8 >> 2, lq = ((c8 & 3) << 4) | row;
          *(uint4*)(sm.c.bfrag + ((kkb * 64 + lq) << 3)) = v;
        }
      }
      __syncthreads();
      // GEMM: wave w -> M rows w*16..+16, N=16 (full M=128 x N=16 tile)
      {
        const u16* Ab = Ac + (size_t)(w * 16 + l15) * Kc + qd * 8;
        const u16* Bb = sm.c.bfrag + (lane << 3);
        v4f acc = (v4f){0.f, 0.f, 0.f, 0.f};
        const int NKB = Kc >> 5;
#pragma unroll 4
        for (int kkb = 0; kkb < NKB; ++kkb)
          acc = mfma16(ld8(Ab + kkb * 32), ld8(Bb + (kkb << 9)), acc);
#pragma unroll
        for (int r = 0; r < 4; ++r)
          sm.c.glds[w * 16 + qd * 4 + r][l15] = acc[r];
      }
      __syncthreads();
      // pointwise: thread = (m=cm_, jl=cjl); hdim jg = wg*4+jl
      {
        float gi = sm.c.glds[cm_][0 * 4 + cjl] + cbias[ci][0];
        float gf = sm.c.glds[cm_][1 * 4 + cjl] + cbias[ci][1];
        float gg = sm.c.glds[cm_][2 * 4 + cjl] + cbias[ci][2];
        float go = sm.c.glds[cm_][3 * 4 + cjl] + cbias[ci][3];
        float cv = sigm(gf) * cstate[ci] + sigm(gi) * tanhf(gg);
        cstate[ci] = cv;
        u16 hb = f2bf(sigm(go) * tanhf(cv));
        const int jg = wg * 4 + cjl;
        A.hd[(size_t)((ci * 2 + (p ^ 1)) * 128 + cm_) * 1024 + jg] = hb;
        if (ci == 0) A.ad2[(size_t)cm_ * 3072 + 1024 + jg] = hb;
        else if (ci == 1) A.ad3[(size_t)cm_ * 3072 + 1024 + jg] = hb;
      }
      gbar(A.flags, 256, wg, bt++);
    }
  }
}

// ---------------- host ----------------
extern "C" void kernel_launch(void* const* d_in, const int* in_sizes, int n_in,
                              void* d_out, int out_size, void* d_ws, size_t ws_size,
                              hipStream_t stream) {
  char* ws = (char*)d_ws;
  size_t off = 0;
  auto alc = [&](size_t bytes) -> char* {
    char* pp = ws + off;
    off += (bytes + 255) & ~(size_t)255;
    return pp;
  };
  u16* XB = (u16*)alc(2097152ull * 2);
  u16* WF0 = (u16*)alc(2359296ull * 2);
  float* BF0 = (float*)alc(4096ull * 4);
  u16* WF1 = (u16*)alc(6291456ull * 2);
  float* BF1 = (float*)alc(4096ull * 4);
  u16* H0 = (u16*)alc(33554432ull * 2);
  u16* EO = (u16*)alc(33554432ull * 2);
  u16* HS0 = (u16*)alc(262144ull * 2);
  u16* HS1 = (u16*)alc(262144ull * 2);
  u16* WQ = (u16*)alc(3145728ull * 2);
  u16* WOUT = (u16*)alc(65536ull * 2);
  u16* WD1 = (u16*)alc(8650752ull * 2);
  float* BD1 = (float*)alc(4096ull * 4);
  u16* WD2 = (u16*)alc(12582912ull * 2);
  float* BD2 = (float*)alc(4096ull * 4);
  u16* WD3 = (u16*)alc(12582912ull * 2);
  float* BD3 = (float*)alc(4096ull * 4);
  u16* QP = (u16*)alc(2097152ull * 2);
  u16* HD = (u16*)alc(786432ull * 2);
  u16* AD1 = (u16*)alc(270336ull * 2);
  u16* AD2 = (u16*)alc(393216ull * 2);
  u16* AD3 = (u16*)alc(393216ull * 2);
  u32* FLAGS = (u32*)alc(1536ull * 4);

  // zero state buffers (ws is poisoned before every call)
  k_zero<<<2, 256, 0, stream>>>((uint4*)FLAGS, 384);
  k_zero<<<1024, 256, 0, stream>>>((uint4*)QP, 262144);
  k_zero<<<128, 256, 0, stream>>>((uint4*)HS0, 32768);
  k_zero<<<128, 256, 0, stream>>>((uint4*)HS1, 32768);
  k_zero<<<384, 256, 0, stream>>>((uint4*)HD, 98304);

  // pack weights / inputs to bf16
  k_cvt<<<2048, 256, 0, stream>>>((const float*)d_in[0], XB, 2097152);
  k_cvt<<<64, 256, 0, stream>>>((const float*)d_in[22], WOUT, 65536);
  k_pack_enc<<<4096, 256, 0, stream>>>((const float*)d_in[1], (const float*)d_in[2],
                                       (const float*)d_in[3], WF0, BF0, 64);
  k_pack_enc<<<4096, 256, 0, stream>>>((const float*)d_in[4], (const float*)d_in[5],
                                       (const float*)d_in[6], WF1, BF1, 1024);
  k_pack_attnT<<<3072, 256, 0, stream>>>((const float*)d_in[7], (const float*)d_in[9],
                                         (const float*)d_in[11], WQ);
  k_pack_dec<<<4096, 256, 0, stream>>>((const float*)d_in[13], (const float*)d_in[14],
                                       (const float*)d_in[15], WD1, BD1, 1088);
  k_pack_dec<<<4096, 256, 0, stream>>>((const float*)d_in[16], (const float*)d_in[17],
                                       (const float*)d_in[18], WD2, BD2, 2048);
  k_pack_dec<<<4096, 256, 0, stream>>>((const float*)d_in[19], (const float*)d_in[20],
                                       (const float*)d_in[21], WD3, BD3, 2048);

  // encoder layers (persistent, 256 WGs x 512 threads each)
  k_enc<<<256, 512, 0, stream>>>(XB, 64, WF0, BF0, HS0, H0, FLAGS);
  k_enc<<<256, 512, 0, stream>>>(H0, 1024, WF1, BF1, HS1, EO, FLAGS + 512);

  // decoder (persistent, 256 WGs x 512 threads)
  DecArgs da;
  da.x = (const float*)d_in[0];
  da.outb = (const float*)d_in[23];
  da.dout = (float*)d_out;
  da.eo = EO; da.wq = WQ; da.wout = WOUT;
  da.wd1 = WD1; da.wd2 = WD2; da.wd3 = WD3;
  da.bd1 = BD1; da.bd2 = BD2; da.bd3 = BD3;
  da.qp = QP; da.hd = HD; da.ad1 = AD1; da.ad2 = AD2; da.ad3 = AD3;
  da.flags = FLAGS + 1024;
  k_dec<<<256, 512, 0, stream>>>(da);
}